// Round 1
// baseline (4596.318 us; speedup 1.0000x reference)
//
#include <hip/hip_runtime.h>
#include <cstdint>
#include <cstddef>

#define TK_CAP 2048

__device__ __forceinline__ uint32_t f2u(float f) {
  uint32_t b = __float_as_uint(f);
  return (b & 0x80000000u) ? ~b : (b | 0x80000000u);
}

// ---------------------------------------------------------------- GEMM
// C[M,N] = A[M,K] @ B[K,N] + addv[N]; M%128==0, K%16==0, N guarded.
// 128x128 block tile, 256 threads, 8x8 per-thread micro-tile, BK=16.
__global__ __launch_bounds__(256)
void gemm_tile(const float* __restrict__ A, const float* __restrict__ Bm,
               const float* __restrict__ addv, float* __restrict__ C,
               int M, int N, int K) {
  __shared__ float As[16][128];
  __shared__ float Bs[16][128];
  const int tid = threadIdx.x;
  const int tx = tid & 15, ty = tid >> 4;
  const int row0 = blockIdx.x * 128;
  const int col0 = blockIdx.y * 128;
  float acc[8][8];
#pragma unroll
  for (int i = 0; i < 8; ++i)
#pragma unroll
    for (int j = 0; j < 8; ++j) acc[i][j] = 0.f;

  for (int k0 = 0; k0 < K; k0 += 16) {
#pragma unroll
    for (int i = 0; i < 2; ++i) {  // A tile 128x16, store k-major
      int lin = tid * 2 + i;
      int ar = lin >> 2, ac = (lin & 3) << 2;
      float4 v = *reinterpret_cast<const float4*>(&A[(size_t)(row0 + ar) * K + k0 + ac]);
      As[ac + 0][ar] = v.x; As[ac + 1][ar] = v.y;
      As[ac + 2][ar] = v.z; As[ac + 3][ar] = v.w;
    }
#pragma unroll
    for (int i = 0; i < 2; ++i) {  // B tile 16x128
      int lin = tid * 2 + i;
      int br = lin >> 5, bc = (lin & 31) << 2;
      int gc = col0 + bc;
      float4 v = make_float4(0.f, 0.f, 0.f, 0.f);
      if (gc < N) v = *reinterpret_cast<const float4*>(&Bm[(size_t)(k0 + br) * N + gc]);
      *reinterpret_cast<float4*>(&Bs[br][bc]) = v;
    }
    __syncthreads();
#pragma unroll
    for (int k = 0; k < 16; ++k) {
      float a[8], b[8];
      *reinterpret_cast<float4*>(&a[0]) = *reinterpret_cast<const float4*>(&As[k][ty * 8]);
      *reinterpret_cast<float4*>(&a[4]) = *reinterpret_cast<const float4*>(&As[k][ty * 8 + 4]);
      *reinterpret_cast<float4*>(&b[0]) = *reinterpret_cast<const float4*>(&Bs[k][tx * 8]);
      *reinterpret_cast<float4*>(&b[4]) = *reinterpret_cast<const float4*>(&Bs[k][tx * 8 + 4]);
#pragma unroll
      for (int i = 0; i < 8; ++i)
#pragma unroll
        for (int j = 0; j < 8; ++j)
          acc[i][j] = fmaf(a[i], b[j], acc[i][j]);
    }
    __syncthreads();
  }
#pragma unroll
  for (int i = 0; i < 8; ++i) {
    int row = row0 + ty * 8 + i;
#pragma unroll
    for (int jj = 0; jj < 2; ++jj) {
      int col = col0 + tx * 8 + jj * 4;
      if (col < N) {
        float4 o;
        o.x = acc[i][jj * 4 + 0] + addv[col + 0];
        o.y = acc[i][jj * 4 + 1] + addv[col + 1];
        o.z = acc[i][jj * 4 + 2] + addv[col + 2];
        o.w = acc[i][jj * 4 + 3] + addv[col + 3];
        *reinterpret_cast<float4*>(&C[(size_t)row * N + col]) = o;
      }
    }
  }
}

// ---------------------------------------------------- LayerNorm + exact GELU
__global__ __launch_bounds__(256)
void ln_gelu(float* __restrict__ h, const float* __restrict__ gamma,
             const float* __restrict__ beta) {
  const int row = blockIdx.x;
  float* p = h + (size_t)row * 512;
  const int tid = threadIdx.x;
  float2 v = reinterpret_cast<float2*>(p)[tid];
  float s = v.x + v.y;
  float q = v.x * v.x + v.y * v.y;
#pragma unroll
  for (int o = 32; o > 0; o >>= 1) {
    s += __shfl_down(s, o);
    q += __shfl_down(q, o);
  }
  __shared__ float red[10];
  const int wid = tid >> 6, lane = tid & 63;
  if (lane == 0) { red[wid] = s; red[4 + wid] = q; }
  __syncthreads();
  if (tid == 0) {
    float S = red[0] + red[1] + red[2] + red[3];
    float Q = red[4] + red[5] + red[6] + red[7];
    float mean = S * (1.f / 512.f);
    red[8] = mean;
    red[9] = Q * (1.f / 512.f) - mean * mean;
  }
  __syncthreads();
  float mean = red[8];
  float r = 1.0f / sqrtf(red[9] + 1e-5f);
  float g0 = gamma[2 * tid], g1 = gamma[2 * tid + 1];
  float be0 = beta[2 * tid], be1 = beta[2 * tid + 1];
  float x0 = (v.x - mean) * r * g0 + be0;
  float x1 = (v.y - mean) * r * g1 + be1;
  x0 = 0.5f * x0 * (1.f + erff(x0 * 0.70710678118654752f));
  x1 = 0.5f * x1 * (1.f + erff(x1 * 0.70710678118654752f));
  reinterpret_cast<float2*>(p)[tid] = make_float2(x0, x1);
}

// -------------------------------------------- extra[j] = b2 + 0.3*comp + 0.1/(ema+1e-6)
__global__ void make_extra(const float* __restrict__ b2, const float* __restrict__ comp,
                           const float* __restrict__ ema, float* __restrict__ extra, int n) {
  int i = blockIdx.x * 256 + threadIdx.x;
  if (i < n) extra[i] = b2[i] + 0.3f * comp[i] + 0.1f * (1.0f / (ema[i] + 1e-6f));
}

__global__ void ema_update(const float* __restrict__ ema, const float* __restrict__ cntv,
                           float* __restrict__ out, int n) {
  int i = blockIdx.x * 256 + threadIdx.x;
  if (i < n) out[i] = 0.99f * ema[i] + 0.01f * cntv[i];
}

// ---------------------------------------------------------------- top-k
union TKShared {
  uint32_t hist[4][4096];
  unsigned long long keys[TK_CAP];
};

// scan hist (4096 bins) from top for the bin where cumulative count reaches 64
__device__ void tk_find_bin(uint32_t* hist, uint32_t* csum, uint32_t* misc,
                            uint32_t start_acc, int tid) {
  uint32_t part = 0;
#pragma unroll
  for (int j = 0; j < 16; ++j) part += hist[tid * 16 + j];
  csum[tid] = part;
  __syncthreads();
  if (tid == 0) {
    uint32_t acc = start_acc;
    int chunk;
    for (chunk = 255; chunk > 0; --chunk) {
      if (acc + csum[chunk] >= 64u) break;
      acc += csum[chunk];
    }
    int bin;
    for (bin = chunk * 16 + 15; bin > chunk * 16; --bin) {
      if (acc + hist[bin] >= 64u) break;
      acc += hist[bin];
    }
    misc[1] = (uint32_t)bin;
    misc[2] = acc;  // count strictly above bin
  }
  __syncthreads();
}

__global__ __launch_bounds__(256)
void topk_kernel(const float* __restrict__ scores, float* __restrict__ mask,
                 float* __restrict__ topidx, float* __restrict__ cntv) {
  const int N = 50000;
  const int row = blockIdx.x;
  const int tid = threadIdx.x;
  const float* p = scores + (size_t)row * N;
  __shared__ TKShared sm;
  __shared__ uint32_t csum[256];
  __shared__ uint32_t misc[4];

  for (int i = tid; i < 4 * 4096; i += 256) (&sm.hist[0][0])[i] = 0u;
  if (tid == 0) misc[0] = 0u;
  __syncthreads();

  const int wid = tid >> 6;
  const float4* p4 = reinterpret_cast<const float4*>(p);
  const int n4 = N / 4;
  for (int i = tid; i < n4; i += 256) {
    float4 v = p4[i];
    atomicAdd(&sm.hist[wid][f2u(v.x) >> 20], 1u);
    atomicAdd(&sm.hist[wid][f2u(v.y) >> 20], 1u);
    atomicAdd(&sm.hist[wid][f2u(v.z) >> 20], 1u);
    atomicAdd(&sm.hist[wid][f2u(v.w) >> 20], 1u);
  }
  __syncthreads();
  for (int i = tid; i < 4096; i += 256)
    sm.hist[0][i] += sm.hist[1][i] + sm.hist[2][i] + sm.hist[3][i];
  __syncthreads();

  tk_find_bin(sm.hist[0], csum, misc, 0u, tid);
  const uint32_t binB = misc[1];
  const uint32_t thr = binB << 20;

  // collect candidates (keys alias hist storage; hist no longer needed)
  for (int i = tid; i < n4; i += 256) {
    float4 v = p4[i];
    float vals[4] = {v.x, v.y, v.z, v.w};
#pragma unroll
    for (int c = 0; c < 4; ++c) {
      uint32_t u = f2u(vals[c]);
      if (u >= thr) {
        uint32_t pos = atomicAdd(&misc[0], 1u);
        if (pos < TK_CAP)
          sm.keys[pos] = ((unsigned long long)u << 32) | (uint32_t)(~(uint32_t)(i * 4 + c));
      }
    }
  }
  __syncthreads();
  uint32_t cc = misc[0];

  if (cc > TK_CAP) {  // rare: refine threshold to 24-bit prefix
    for (int i = tid; i < 4096; i += 256) sm.hist[0][i] = 0u;
    __syncthreads();
    for (int i = tid; i < N; i += 256) {
      uint32_t u = f2u(p[i]);
      if ((u >> 20) == binB) atomicAdd(&sm.hist[0][(u >> 8) & 0xFFFu], 1u);
    }
    __syncthreads();
    uint32_t accA = misc[2];
    tk_find_bin(sm.hist[0], csum, misc, accA, tid);
    uint32_t binB2 = misc[1];
    uint32_t thr2 = (binB << 20) | (binB2 << 8);
    if (tid == 0) misc[0] = 0u;
    __syncthreads();
    for (int i = tid; i < n4; i += 256) {
      float4 v = p4[i];
      float vals[4] = {v.x, v.y, v.z, v.w};
#pragma unroll
      for (int c = 0; c < 4; ++c) {
        uint32_t u = f2u(vals[c]);
        if (u >= thr2) {
          uint32_t pos = atomicAdd(&misc[0], 1u);
          if (pos < TK_CAP)
            sm.keys[pos] = ((unsigned long long)u << 32) | (uint32_t)(~(uint32_t)(i * 4 + c));
        }
      }
    }
    __syncthreads();
    cc = misc[0];
    if (cc > TK_CAP) cc = TK_CAP;
  }

  // bitonic sort descending over S >= cc (key = value-bits : ~index)
  int S = 64;
  while (S < (int)cc) S <<= 1;
  for (int i = tid; i < S; i += 256)
    if (i >= (int)cc) sm.keys[i] = 0ull;
  __syncthreads();
  for (int kk = 2; kk <= S; kk <<= 1) {
    for (int j = kk >> 1; j > 0; j >>= 1) {
      for (int i = tid; i < S; i += 256) {
        int ixj = i ^ j;
        if (ixj > i) {
          unsigned long long a = sm.keys[i];
          unsigned long long b = sm.keys[ixj];
          bool desc = ((i & kk) == 0);
          if (desc ? (a < b) : (a > b)) { sm.keys[i] = b; sm.keys[ixj] = a; }
        }
      }
      __syncthreads();
    }
  }

  if (tid < 64) {
    unsigned long long kx = sm.keys[tid];
    uint32_t idx = ~((uint32_t)kx);
    topidx[row * 64 + tid] = (float)idx;
    mask[(size_t)row * N + idx] = 1.0f;
    atomicAdd(&cntv[idx], 1.0f);
  }
}

// ---------------------------------------------------------------- launch
extern "C" void kernel_launch(void* const* d_in, const int* in_sizes, int n_in,
                              void* d_out, int out_size, void* d_ws, size_t ws_size,
                              hipStream_t stream) {
  const float* z     = (const float*)d_in[0];
  const float* w1    = (const float*)d_in[1];
  const float* b1    = (const float*)d_in[2];
  const float* gamma = (const float*)d_in[3];
  const float* beta  = (const float*)d_in[4];
  const float* w2    = (const float*)d_in[5];
  const float* b2    = (const float*)d_in[6];
  const float* comp  = (const float*)d_in[7];
  const float* ema   = (const float*)d_in[8];

  const int B = 4096, H = 1024, Hh = 512, N = 50000, K = 64;

  float* out_mask   = (float*)d_out;                    // B*N
  float* out_topidx = out_mask + (size_t)B * N;         // B*K
  float* out_scores = out_topidx + (size_t)B * K;       // B*N
  float* out_ema    = out_scores + (size_t)B * N;       // N

  float* h     = (float*)d_ws;                          // B*Hh floats
  float* extra = h + (size_t)B * Hh;                    // N
  float* cntv  = extra + N;                             // N

  hipMemsetAsync(out_mask, 0, (size_t)B * N * sizeof(float), stream);
  hipMemsetAsync(cntv, 0, (size_t)N * sizeof(float), stream);

  make_extra<<<(N + 255) / 256, 256, 0, stream>>>(b2, comp, ema, extra, N);

  // GEMM1: h = z @ w1 + b1   [4096,1024]x[1024,512]
  gemm_tile<<<dim3(B / 128, Hh / 128), 256, 0, stream>>>(z, w1, b1, h, B, Hh, H);

  ln_gelu<<<B, 256, 0, stream>>>(h, gamma, beta);

  // GEMM2: scores = h @ w2 + extra   [4096,512]x[512,50000]
  gemm_tile<<<dim3(B / 128, (N + 127) / 128), 256, 0, stream>>>(h, w2, extra, out_scores,
                                                                B, N, Hh);

  topk_kernel<<<B, 256, 0, stream>>>(out_scores, out_mask, out_topidx, cntv);

  ema_update<<<(N + 255) / 256, 256, 0, stream>>>(ema, cntv, out_ema, N);
}

// Round 5
// 3314.165 us; speedup vs baseline: 1.3869x; 1.3869x over previous
//
#include <hip/hip_runtime.h>
#include <cstdint>
#include <cstddef>

#define TK_CAP 2048

typedef __attribute__((ext_vector_type(8))) _Float16 f16x8;
typedef __attribute__((ext_vector_type(2))) _Float16 f16x2;
typedef __attribute__((ext_vector_type(4))) float f32x4;

typedef __attribute__((address_space(3))) void lds_void;
typedef __attribute__((address_space(1))) const void gbl_void;
#define GLDS16(g, l) __builtin_amdgcn_global_load_lds((gbl_void*)(g), (lds_void*)(l), 16, 0, 0)

__device__ __forceinline__ uint32_t f2u(float f) {
  uint32_t b = __float_as_uint(f);
  return (b & 0x80000000u) ? ~b : (b | 0x80000000u);
}

// ---------------------------------------------------------------- fp32 GEMM (GEMM1 only)
__global__ __launch_bounds__(256)
void gemm_tile(const float* __restrict__ A, const float* __restrict__ Bm,
               const float* __restrict__ addv, float* __restrict__ C,
               int M, int N, int K) {
  __shared__ float As[16][128];
  __shared__ float Bs[16][128];
  const int tid = threadIdx.x;
  const int tx = tid & 15, ty = tid >> 4;
  const int row0 = blockIdx.x * 128;
  const int col0 = blockIdx.y * 128;
  float acc[8][8];
#pragma unroll
  for (int i = 0; i < 8; ++i)
#pragma unroll
    for (int j = 0; j < 8; ++j) acc[i][j] = 0.f;

  for (int k0 = 0; k0 < K; k0 += 16) {
#pragma unroll
    for (int i = 0; i < 2; ++i) {
      int lin = tid * 2 + i;
      int ar = lin >> 2, ac = (lin & 3) << 2;
      float4 v = *reinterpret_cast<const float4*>(&A[(size_t)(row0 + ar) * K + k0 + ac]);
      As[ac + 0][ar] = v.x; As[ac + 1][ar] = v.y;
      As[ac + 2][ar] = v.z; As[ac + 3][ar] = v.w;
    }
#pragma unroll
    for (int i = 0; i < 2; ++i) {
      int lin = tid * 2 + i;
      int br = lin >> 5, bc = (lin & 31) << 2;
      int gc = col0 + bc;
      float4 v = make_float4(0.f, 0.f, 0.f, 0.f);
      if (gc < N) v = *reinterpret_cast<const float4*>(&Bm[(size_t)(k0 + br) * N + gc]);
      *reinterpret_cast<float4*>(&Bs[br][bc]) = v;
    }
    __syncthreads();
#pragma unroll
    for (int k = 0; k < 16; ++k) {
      float a[8], b[8];
      *reinterpret_cast<float4*>(&a[0]) = *reinterpret_cast<const float4*>(&As[k][ty * 8]);
      *reinterpret_cast<float4*>(&a[4]) = *reinterpret_cast<const float4*>(&As[k][ty * 8 + 4]);
      *reinterpret_cast<float4*>(&b[0]) = *reinterpret_cast<const float4*>(&Bs[k][tx * 8]);
      *reinterpret_cast<float4*>(&b[4]) = *reinterpret_cast<const float4*>(&Bs[k][tx * 8 + 4]);
#pragma unroll
      for (int i = 0; i < 8; ++i)
#pragma unroll
        for (int j = 0; j < 8; ++j)
          acc[i][j] = fmaf(a[i], b[j], acc[i][j]);
    }
    __syncthreads();
  }
#pragma unroll
  for (int i = 0; i < 8; ++i) {
    int row = row0 + ty * 8 + i;
#pragma unroll
    for (int jj = 0; jj < 2; ++jj) {
      int col = col0 + tx * 8 + jj * 4;
      if (col < N) {
        float4 o;
        o.x = acc[i][jj * 4 + 0] + addv[col + 0];
        o.y = acc[i][jj * 4 + 1] + addv[col + 1];
        o.z = acc[i][jj * 4 + 2] + addv[col + 2];
        o.w = acc[i][jj * 4 + 3] + addv[col + 3];
        *reinterpret_cast<float4*>(&C[(size_t)row * N + col]) = o;
      }
    }
  }
}

// ------------------------------------------------ LN + exact GELU + fp16 2-split
// Acat[row][0:512]=hi, [512:1024]=hi/32, [1024:1536]=lo*32
__global__ __launch_bounds__(256)
void ln_gelu_split(const float* __restrict__ h, const float* __restrict__ gamma,
                   const float* __restrict__ beta, _Float16* __restrict__ Acat) {
  const int row = blockIdx.x;
  const float* p = h + (size_t)row * 512;
  const int tid = threadIdx.x;
  float2 v = reinterpret_cast<const float2*>(p)[tid];
  float s = v.x + v.y;
  float q = v.x * v.x + v.y * v.y;
#pragma unroll
  for (int o = 32; o > 0; o >>= 1) {
    s += __shfl_down(s, o);
    q += __shfl_down(q, o);
  }
  __shared__ float red[10];
  const int wid = tid >> 6, lane = tid & 63;
  if (lane == 0) { red[wid] = s; red[4 + wid] = q; }
  __syncthreads();
  if (tid == 0) {
    float S = red[0] + red[1] + red[2] + red[3];
    float Q = red[4] + red[5] + red[6] + red[7];
    float mean = S * (1.f / 512.f);
    red[8] = mean;
    red[9] = Q * (1.f / 512.f) - mean * mean;
  }
  __syncthreads();
  float mean = red[8];
  float r = 1.0f / sqrtf(red[9] + 1e-5f);
  float g0 = gamma[2 * tid], g1 = gamma[2 * tid + 1];
  float be0 = beta[2 * tid], be1 = beta[2 * tid + 1];
  float x0 = (v.x - mean) * r * g0 + be0;
  float x1 = (v.y - mean) * r * g1 + be1;
  x0 = 0.5f * x0 * (1.f + erff(x0 * 0.70710678118654752f));
  x1 = 0.5f * x1 * (1.f + erff(x1 * 0.70710678118654752f));
  _Float16 h0 = (_Float16)x0, h1 = (_Float16)x1;
  _Float16 s0 = (_Float16)((float)h0 * 0.03125f), s1 = (_Float16)((float)h1 * 0.03125f);
  _Float16 l0 = (_Float16)((x0 - (float)h0) * 32.0f), l1 = (_Float16)((x1 - (float)h1) * 32.0f);
  _Float16* base = Acat + (size_t)row * 1536 + 2 * tid;
  *reinterpret_cast<f16x2*>(base)        = (f16x2){h0, h1};
  *reinterpret_cast<f16x2*>(base + 512)  = (f16x2){s0, s1};
  *reinterpret_cast<f16x2*>(base + 1024) = (f16x2){l0, l1};
}

// ------------------------------------------------ w2 [512][50000] -> Bt [50048][1536] fp16
// Bt[n][0:512]=hi, [512:1024]=lo*32, [1024:1536]=hi/32 (transpose via LDS)
__global__ __launch_bounds__(256)
void convB(const float* __restrict__ w2, _Float16* __restrict__ Bt) {
  __shared__ float t[64][65];
  const int n0 = blockIdx.x * 64, k0 = blockIdx.y * 64;
  const int tid = threadIdx.x;
  const int lk = tid >> 4;
  const int ln = (tid & 15) * 4;
#pragma unroll
  for (int i = 0; i < 4; ++i) {
    int k = k0 + lk + i * 16;
    int n = n0 + ln;
    float4 v = make_float4(0.f, 0.f, 0.f, 0.f);
    if (n < 50000) v = *reinterpret_cast<const float4*>(&w2[(size_t)k * 50000 + n]);
    t[lk + i * 16][ln + 0] = v.x; t[lk + i * 16][ln + 1] = v.y;
    t[lk + i * 16][ln + 2] = v.z; t[lk + i * 16][ln + 3] = v.w;
  }
  __syncthreads();
  const int nl = tid >> 2, kk = (tid & 3) * 16;
  const int n = n0 + nl;
  if (n < 50000) {
    _Float16 hi[16], his[16], lo[16];
#pragma unroll
    for (int i = 0; i < 16; ++i) {
      float w = t[kk + i][nl];
      _Float16 hh = (_Float16)w;
      hi[i]  = hh;
      his[i] = (_Float16)((float)hh * 0.03125f);
      lo[i]  = (_Float16)((w - (float)hh) * 32.0f);
    }
    _Float16* b = Bt + (size_t)n * 1536 + k0 + kk;
    *reinterpret_cast<f16x8*>(b + 0)        = *reinterpret_cast<f16x8*>(&hi[0]);
    *reinterpret_cast<f16x8*>(b + 8)        = *reinterpret_cast<f16x8*>(&hi[8]);
    *reinterpret_cast<f16x8*>(b + 512)      = *reinterpret_cast<f16x8*>(&lo[0]);
    *reinterpret_cast<f16x8*>(b + 520)      = *reinterpret_cast<f16x8*>(&lo[8]);
    *reinterpret_cast<f16x8*>(b + 1024)     = *reinterpret_cast<f16x8*>(&his[0]);
    *reinterpret_cast<f16x8*>(b + 1032)     = *reinterpret_cast<f16x8*>(&his[8]);
  }
}

// ---------------------------------------------------------------- MFMA GEMM2
// C[4096][50000] = Acat[4096][1536] @ Bt[50048][1536]^T + extra, fp16 split inputs
__global__ __launch_bounds__(256)
void gemm2_f16(const _Float16* __restrict__ A, const _Float16* __restrict__ Bt,
               const float* __restrict__ extra, float* __restrict__ C) {
  const int K = 1536;
  __shared__ _Float16 As[4096];  // 128 rows x 32 k, swizzled 16B units
  __shared__ _Float16 Bs[4096];
  const int tid = threadIdx.x;
  const int wid = tid >> 6, lane = tid & 63;

  // XCD-chunked bijective swizzle: nwg = 32*391 = 12512, 12512 % 8 == 0.
  const int L = blockIdx.x + gridDim.x * blockIdx.y;
  const int cpx = (gridDim.x * gridDim.y) >> 3;  // 1564
  const int swz = (L & 7) * cpx + (L >> 3);
  const int row0 = (swz & 31) * 128;   // gridDim.x == 32
  const int col0 = (swz >> 5) * 128;
  const int wr = wid >> 1, wc = wid & 1;

  // staging: chunk = wid*2+j covers LDS 16B-units [chunk*64, chunk*64+64)
  // unit s holds element (r = s>>2, kchunk = (s&3) ^ ((r>>1)&3))
  const _Float16* gA[2];
  const _Float16* gB[2];
#pragma unroll
  for (int j = 0; j < 2; ++j) {
    int s = (wid * 2 + j) * 64 + lane;
    int r = s >> 2, c = s & 3;
    int cc = c ^ ((r >> 1) & 3);
    gA[j] = A  + (size_t)(row0 + r) * K + cc * 8;
    gB[j] = Bt + (size_t)(col0 + r) * K + cc * 8;
  }
  char* AsB = (char*)As;
  char* BsB = (char*)Bs;

  // frag read byte offsets (swizzled)
  int aoff[4], boff[4];
  const int crd = lane >> 4;
#pragma unroll
  for (int i = 0; i < 4; ++i) {
    int r = wr * 64 + i * 16 + (lane & 15);
    aoff[i] = r * 64 + (crd ^ ((r >> 1) & 3)) * 16;
    int n = wc * 64 + i * 16 + (lane & 15);
    boff[i] = n * 64 + (crd ^ ((n >> 1) & 3)) * 16;
  }

  f32x4 acc[4][4];
#pragma unroll
  for (int i = 0; i < 4; ++i)
#pragma unroll
    for (int j = 0; j < 4; ++j) acc[i][j] = (f32x4)0.0f;

  // prologue stage k=0
#pragma unroll
  for (int j = 0; j < 2; ++j) {
    GLDS16(gA[j], AsB + (wid * 2 + j) * 1024);
    GLDS16(gB[j], BsB + (wid * 2 + j) * 1024);
    gA[j] += 32; gB[j] += 32;
  }

  for (int ks = 0; ks < 48; ++ks) {
    __syncthreads();  // drains vmcnt(0): staged tile visible
    f16x8 af[4], bf[4];
#pragma unroll
    for (int i = 0; i < 4; ++i) {
      af[i] = *reinterpret_cast<const f16x8*>(AsB + aoff[i]);
      bf[i] = *reinterpret_cast<const f16x8*>(BsB + boff[i]);
    }
#pragma unroll
    for (int mi = 0; mi < 4; ++mi)
#pragma unroll
      for (int nj = 0; nj < 4; ++nj)
        acc[mi][nj] = __builtin_amdgcn_mfma_f32_16x16x32_f16(af[mi], bf[nj], acc[mi][nj], 0, 0, 0);
    __syncthreads();  // all reads done; safe to overwrite LDS
    if (ks < 47) {
#pragma unroll
      for (int j = 0; j < 2; ++j) {
        GLDS16(gA[j], AsB + (wid * 2 + j) * 1024);
        GLDS16(gB[j], BsB + (wid * 2 + j) * 1024);
        gA[j] += 32; gB[j] += 32;
      }
    }
  }

  // epilogue: C/D layout col=lane&15, row=(lane>>4)*4+reg  [m89-verified]
  const int lr = lane >> 4, lc = lane & 15;
#pragma unroll
  for (int nj = 0; nj < 4; ++nj) {
    int col = col0 + wc * 64 + nj * 16 + lc;
    bool ok = col < 50000;
    float ex = ok ? extra[col] : 0.f;
    if (ok) {
#pragma unroll
      for (int mi = 0; mi < 4; ++mi) {
        int rbase = row0 + wr * 64 + mi * 16 + lr * 4;
#pragma unroll
        for (int reg = 0; reg < 4; ++reg)
          C[(size_t)(rbase + reg) * 50000 + col] = acc[mi][nj][reg] + ex;
      }
    }
  }
}

// -------------------------------------------- extra / ema
__global__ void make_extra(const float* __restrict__ b2, const float* __restrict__ comp,
                           const float* __restrict__ ema, float* __restrict__ extra, int n) {
  int i = blockIdx.x * 256 + threadIdx.x;
  if (i < n) extra[i] = b2[i] + 0.3f * comp[i] + 0.1f * (1.0f / (ema[i] + 1e-6f));
}

__global__ void ema_update(const float* __restrict__ ema, const float* __restrict__ cntv,
                           float* __restrict__ out, int n) {
  int i = blockIdx.x * 256 + threadIdx.x;
  if (i < n) out[i] = 0.99f * ema[i] + 0.01f * cntv[i];
}

// ---------------------------------------------------------------- top-k
union TKShared {
  uint32_t hist[4][4104];   // +8 pad: spread the 4 copies across banks
  unsigned long long keys[TK_CAP];
};

__device__ void tk_find_bin(uint32_t* hist, uint32_t* csum, uint32_t* misc,
                            uint32_t start_acc, int tid) {
  uint32_t part = 0;
#pragma unroll
  for (int j = 0; j < 16; ++j) part += hist[tid * 16 + j];
  csum[tid] = part;
  __syncthreads();
  if (tid == 0) {
    uint32_t acc = start_acc;
    int chunk;
    for (chunk = 255; chunk > 0; --chunk) {
      if (acc + csum[chunk] >= 64u) break;
      acc += csum[chunk];
    }
    int bin;
    for (bin = chunk * 16 + 15; bin > chunk * 16; --bin) {
      if (acc + hist[bin] >= 64u) break;
      acc += hist[bin];
    }
    misc[1] = (uint32_t)bin;
    misc[2] = acc;
  }
  __syncthreads();
}

__global__ __launch_bounds__(256)
void topk_kernel(const float* __restrict__ scores, float* __restrict__ mask,
                 float* __restrict__ topidx, float* __restrict__ cntv) {
  const int N = 50000;
  const int row = blockIdx.x;
  const int tid = threadIdx.x;
  const float* p = scores + (size_t)row * N;
  __shared__ TKShared sm;
  __shared__ uint32_t csum[256];
  __shared__ uint32_t misc[4];

  for (int i = tid; i < 4 * 4104; i += 256) (&sm.hist[0][0])[i] = 0u;
  if (tid == 0) misc[0] = 0u;
  __syncthreads();

  const int cpy = tid & 3;
  const float4* p4 = reinterpret_cast<const float4*>(p);
  const int n4 = N / 4;
  for (int i = tid; i < n4; i += 256) {
    float4 v = p4[i];
    atomicAdd(&sm.hist[cpy][f2u(v.x) >> 20], 1u);
    atomicAdd(&sm.hist[cpy][f2u(v.y) >> 20], 1u);
    atomicAdd(&sm.hist[cpy][f2u(v.z) >> 20], 1u);
    atomicAdd(&sm.hist[cpy][f2u(v.w) >> 20], 1u);
  }
  __syncthreads();
  for (int i = tid; i < 4096; i += 256)
    sm.hist[0][i] += sm.hist[1][i] + sm.hist[2][i] + sm.hist[3][i];
  __syncthreads();

  tk_find_bin(sm.hist[0], csum, misc, 0u, tid);
  const uint32_t binB = misc[1];
  const uint32_t thr = binB << 20;

  for (int i = tid; i < n4; i += 256) {
    float4 v = p4[i];
    float vals[4] = {v.x, v.y, v.z, v.w};
#pragma unroll
    for (int c = 0; c < 4; ++c) {
      uint32_t u = f2u(vals[c]);
      if (u >= thr) {
        uint32_t pos = atomicAdd(&misc[0], 1u);
        if (pos < TK_CAP)
          sm.keys[pos] = ((unsigned long long)u << 32) | (uint32_t)(~(uint32_t)(i * 4 + c));
      }
    }
  }
  __syncthreads();
  uint32_t cc = misc[0];

  if (cc > TK_CAP) {
    for (int i = tid; i < 4096; i += 256) sm.hist[0][i] = 0u;
    __syncthreads();
    for (int i = tid; i < N; i += 256) {
      uint32_t u = f2u(p[i]);
      if ((u >> 20) == binB) atomicAdd(&sm.hist[0][(u >> 8) & 0xFFFu], 1u);
    }
    __syncthreads();
    uint32_t accA = misc[2];
    tk_find_bin(sm.hist[0], csum, misc, accA, tid);
    uint32_t binB2 = misc[1];
    uint32_t thr2 = (binB << 20) | (binB2 << 8);
    if (tid == 0) misc[0] = 0u;
    __syncthreads();
    for (int i = tid; i < n4; i += 256) {
      float4 v = p4[i];
      float vals[4] = {v.x, v.y, v.z, v.w};
#pragma unroll
      for (int c = 0; c < 4; ++c) {
        uint32_t u = f2u(vals[c]);
        if (u >= thr2) {
          uint32_t pos = atomicAdd(&misc[0], 1u);
          if (pos < TK_CAP)
            sm.keys[pos] = ((unsigned long long)u << 32) | (uint32_t)(~(uint32_t)(i * 4 + c));
        }
      }
    }
    __syncthreads();
    cc = misc[0];
    if (cc > TK_CAP) cc = TK_CAP;
  }

  int S = 64;
  while (S < (int)cc) S <<= 1;
  for (int i = tid; i < S; i += 256)
    if (i >= (int)cc) sm.keys[i] = 0ull;
  __syncthreads();
  for (int kk = 2; kk <= S; kk <<= 1) {
    for (int j = kk >> 1; j > 0; j >>= 1) {
      for (int i = tid; i < S; i += 256) {
        int ixj = i ^ j;
        if (ixj > i) {
          unsigned long long a = sm.keys[i];
          unsigned long long b = sm.keys[ixj];
          bool desc = ((i & kk) == 0);
          if (desc ? (a < b) : (a > b)) { sm.keys[i] = b; sm.keys[ixj] = a; }
        }
      }
      __syncthreads();
    }
  }

  if (tid < 64) {
    unsigned long long kx = sm.keys[tid];
    uint32_t idx = ~((uint32_t)kx);
    topidx[row * 64 + tid] = (float)idx;
    mask[(size_t)row * N + idx] = 1.0f;
    atomicAdd(&cntv[idx], 1.0f);
  }
}

// ---------------------------------------------------------------- launch
extern "C" void kernel_launch(void* const* d_in, const int* in_sizes, int n_in,
                              void* d_out, int out_size, void* d_ws, size_t ws_size,
                              hipStream_t stream) {
  const float* z     = (const float*)d_in[0];
  const float* w1    = (const float*)d_in[1];
  const float* b1    = (const float*)d_in[2];
  const float* gamma = (const float*)d_in[3];
  const float* beta  = (const float*)d_in[4];
  const float* w2    = (const float*)d_in[5];
  const float* b2    = (const float*)d_in[6];
  const float* comp  = (const float*)d_in[7];
  const float* ema   = (const float*)d_in[8];

  const int B = 4096, Hh = 512, N = 50000, K = 64;

  float* out_mask   = (float*)d_out;                    // B*N
  float* out_topidx = out_mask + (size_t)B * N;         // B*K
  float* out_scores = out_topidx + (size_t)B * K;       // B*N
  float* out_ema    = out_scores + (size_t)B * N;       // N

  // big split buffers live in the (not-yet-needed) mask region:
  _Float16* Bt   = (_Float16*)out_mask;                              // 50048*1536*2 = 153.75MB
  _Float16* Acat = (_Float16*)((char*)d_out + (size_t)200 * 1024 * 1024);  // 12.6MB

  float* h     = (float*)d_ws;                          // B*Hh
  float* extra = h + (size_t)B * Hh;                    // N
  float* cntv  = extra + N;                             // N

  hipMemsetAsync(cntv, 0, (size_t)N * sizeof(float), stream);

  convB<<<dim3(782, 8), 256, 0, stream>>>(w2, Bt);
  make_extra<<<(N + 255) / 256, 256, 0, stream>>>(b2, comp, ema, extra, N);

  // GEMM1: h = z @ w1 + b1   [4096,1024]x[1024,512] (fp32 VALU, small)
  gemm_tile<<<dim3(B / 128, Hh / 128), 256, 0, stream>>>(z, w1, b1, h, B, Hh, 1024);

  ln_gelu_split<<<B, 256, 0, stream>>>(h, gamma, beta, Acat);

  // GEMM2 via fp16 2-split MFMA, K'=1536
  gemm2_f16<<<dim3(B / 128, 391), 256, 0, stream>>>(Acat, Bt, extra, out_scores);

  // now reclaim mask region
  hipMemsetAsync(out_mask, 0, (size_t)B * N * sizeof(float), stream);

  topk_kernel<<<B, 256, 0, stream>>>(out_scores, out_mask, out_topidx, cntv);

  ema_update<<<(N + 255) / 256, 256, 0, stream>>>(ema, cntv, out_ema, N);
}